// Round 8
// baseline (18678.676 us; speedup 1.0000x reference)
//
#include <hip/hip_runtime.h>
#include <hip/hip_bf16.h>
#include <math.h>

#define BB 64
#define SS 512
#define EE 256
#define HH 512
#define GG 2048   // 4H
#define NWG 512
#define HSTRIDE 32768                       // floats per phase: 64 b * 512 k
#define DSTRIDE ((size_t)(SS+1)*HSTRIDE)    // floats per direction
#define SWZ(q) ((q) ^ (((q) >> 3) & 7))     // LDS quad swizzle

// ---------------------------------------------------------------------------
// K_pre: fold dense + CRF kernel:  wde[tag][k] = sum_m Wd[k][m]*crfW[m][tag]
// ---------------------------------------------------------------------------
__global__ void k_wde(const float* __restrict__ Wd, const float* __restrict__ bd,
                      const float* __restrict__ crfW, const float* __restrict__ crfb,
                      float* __restrict__ wde, float* __restrict__ bde)
{
  const int idx = blockIdx.x*256 + threadIdx.x;
  if (idx < 9*1024) {
    const int tag = idx >> 10, k = idx & 1023;
    float s = 0.f;
    #pragma unroll
    for (int m = 0; m < 9; ++m) s += Wd[k*9 + m] * crfW[m*9 + tag];
    wde[idx] = s;
  }
  if (idx < 9) {
    float s = crfb[idx];
    #pragma unroll
    for (int m = 0; m < 9; ++m) s += bd[m]*crfW[m*9 + idx];
    bde[idx] = s;
  }
}

// ---------------------------------------------------------------------------
// K2: persistent fused bidirectional LSTM, occupancy-2 variant.
// 512 WGs: wg -> group g = wg&7 (d = wg&1, bq = (wg>>1)&3), cg = wg>>3 (0..63).
// Group = 64 WGs on one XCD (blockIdx%8 round-robin). WG tile = 16 b x 8 cols,
// each thread owns (1 col x 2 gates), K split 16-way by kcc. 2 WGs/CU
// (launch_bounds(256,2), <=256 VGPR, 64.7 KB LDS) -> latency overlap.
// xs (x tile) double-buffered: step p+1's emb staging overlaps step p compute.
// Producer h: LDS-staged 4-B relaxed agent stores; consumer: plain coalesced
// float4 loads ordered behind wave-0 flag poll + barrier. Flags: 1 store/WG.
// h layout: h_all[d][phase 1..512][b][k]; phase-0 slot never read (p=0 skips h).
// ---------------------------------------------------------------------------
__global__ __launch_bounds__(256, 2) void k_lstm(
    const int* __restrict__ inputs, const float* __restrict__ emb,
    const float* __restrict__ Uf, const float* __restrict__ Ub,
    const float* __restrict__ Wf, const float* __restrict__ Wb,
    const float* __restrict__ bf, const float* __restrict__ bb2,
    float* __restrict__ h_all, unsigned int* __restrict__ bars)
{
  const int wg = blockIdx.x;
  const int d  = wg & 1;
  const int bq = (wg >> 1) & 3;
  const int cg = wg >> 3;                    // 0..63
  const float* __restrict__ U    = d ? Ub  : Uf;
  const float* __restrict__ W    = d ? Wb  : Wf;
  const float* __restrict__ bias = d ? bb2 : bf;
  float* __restrict__ h_d = h_all + (size_t)d * DSTRIDE;
  unsigned int* __restrict__ rdy = bars + (wg & 7)*64;   // 64 flags / group

  __shared__ float xs[2][4096];  // [buf][16 b][256 k] quad-swizzled (32 KB)
  __shared__ float hs[8192];     // [16 b][512 k] quad-swizzled (32 KB)
  __shared__ float hst[144];     // [16 b][8 col] stride 9 (out-stage)
  __shared__ int   tok_l[2][16];

  const int tid  = threadIdx.x;
  const int w    = tid >> 6;
  const int lane = tid & 63;
  const int kcc  = lane & 15;
  const int jj   = lane >> 4;
  const int cl   = w*2 + (jj >> 1);          // col-local 0..7
  const int col  = cg*8 + cl;                // this thread's h-column
  const int gp   = (jj & 1) * 2;             // gate pair: 0 -> (i,f), 2 -> (g,o)

  // weights in registers: k-split 16-way by kcc, 2 gates per thread
  float2 ureg[32];   // U[k = kcc*32+i][gp, gp+1 at col]
  #pragma unroll
  for (int i = 0; i < 32; ++i) {
    const float* ur = U + (size_t)(kcc*32 + i)*GG + gp*512 + col;
    ureg[i] = make_float2(ur[0], ur[512]);
  }
  float2 wreg[16];   // W[k = kcc*16+i][gp, gp+1 at col]
  #pragma unroll
  for (int i = 0; i < 16; ++i) {
    const float* wr = W + (size_t)(kcc*16 + i)*GG + gp*512 + col;
    wreg[i] = make_float2(wr[0], wr[512]);
  }
  const float2 breg = make_float2(bias[gp*512 + col], bias[gp*512 + 512 + col]);
  float cst = 0.f;                           // c-state for (b = bq*16+kcc, col)

  // prologue: stage tokens + x tile for p=0 into buffer 0
  {
    const int t0 = d ? 511 : 0;
    if (tid < 16) tok_l[0][tid] = inputs[(bq*16 + tid)*SS + t0];
    __syncthreads();
    #pragma unroll
    for (int r = 0; r < 4; ++r) {
      const int q = r*256 + tid, b = q >> 6, qx = q & 63;
      const float4 v = *(const float4*)&emb[(size_t)tok_l[0][b]*EE + qx*4];
      *(float4*)&xs[0][b*256 + SWZ(qx)*4] = v;
    }
  }

  #pragma unroll 1
  for (int p = 0; p < 512; ++p) {
    const int pb = p & 1;
    const float* __restrict__ hp = h_d + (size_t)p     * HSTRIDE;
    float* __restrict__ hn       = h_d + (size_t)(p+1) * HSTRIDE;

    // wave 0 polls this group's 64 producer flags (h(p) ready)
    if (p && w == 0) {
      for (;;) {
        const unsigned int v = __hip_atomic_load(&rdy[lane], __ATOMIC_RELAXED,
                                                 __HIP_MEMORY_SCOPE_AGENT);
        if (__all((int)(v >= (unsigned)p))) break;
        __builtin_amdgcn_s_sleep(1);
      }
    }
    __syncthreads();                         // h(p) visible; xs[pb] staged

    // issue h(p) plain coalesced loads (latency hidden by x@W below)
    float4 hld4[8];
    if (p) {
      #pragma unroll
      for (int r = 0; r < 8; ++r) {
        const int q = r*256 + tid, b = q >> 7, qh = q & 127;
        hld4[r] = *(const float4*)&hp[(size_t)(bq*16 + b)*HH + qh*4];
      }
    }

    // fetch next step's tokens (consumed after the next barrier)
    {
      int tn = d ? (510 - p) : (p + 1);
      tn = tn < 0 ? 0 : (tn > 511 ? 511 : tn);
      if (tid < 16) tok_l[pb ^ 1][tid] = inputs[(bq*16 + tid)*SS + tn];
    }

    float part[16][2];
    #pragma unroll
    for (int b = 0; b < 16; ++b) { part[b][0] = 0.f; part[b][1] = 0.f; }

    // x @ W  (K = 256, 16 k per thread, 2 gates)
    #pragma unroll
    for (int b = 0; b < 16; ++b) {
      const float* xrow = &xs[pb][b*256];
      #pragma unroll
      for (int i = 0; i < 4; ++i) {
        const int q = kcc*4 + i;
        const float4 hv = *(const float4*)&xrow[SWZ(q)*4];
        const float2 w0 = wreg[i*4+0], w1 = wreg[i*4+1], w2 = wreg[i*4+2], w3 = wreg[i*4+3];
        part[b][0] += hv.x*w0.x + hv.y*w1.x + hv.z*w2.x + hv.w*w3.x;
        part[b][1] += hv.x*w0.y + hv.y*w1.y + hv.z*w2.y + hv.w*w3.y;
      }
    }

    // park h(p) into LDS (vmcnt wait auto-inserted here)
    if (p) {
      #pragma unroll
      for (int r = 0; r < 8; ++r) {
        const int q = r*256 + tid, b = q >> 7, qh = q & 127;
        *(float4*)&hs[b*512 + SWZ(qh)*4] = hld4[r];
      }
    }
    __syncthreads();                         // hs ready; tok[pb^1] ready

    if (p) {
      // h @ U  (K = 512, 32 k per thread, 2 gates)
      #pragma unroll
      for (int b = 0; b < 16; ++b) {
        const float* hrow = &hs[b*512];
        #pragma unroll
        for (int i = 0; i < 8; ++i) {
          const int q = kcc*8 + i;
          const float4 hv = *(const float4*)&hrow[SWZ(q)*4];
          const float2 u0 = ureg[i*4+0], u1 = ureg[i*4+1], u2 = ureg[i*4+2], u3 = ureg[i*4+3];
          part[b][0] += hv.x*u0.x + hv.y*u1.x + hv.z*u2.x + hv.w*u3.x;
          part[b][1] += hv.x*u0.y + hv.y*u1.y + hv.z*u2.y + hv.w*u3.y;
        }
      }
    }

    // stage next step's x tile (overlaps with reduce below; off critical chain)
    #pragma unroll
    for (int r = 0; r < 4; ++r) {
      const int q = r*256 + tid, b = q >> 6, qx = q & 63;
      const float4 v = *(const float4*)&emb[(size_t)tok_l[pb ^ 1][b]*EE + qx*4];
      *(float4*)&xs[pb ^ 1][b*256 + SWZ(qx)*4] = v;
    }

    // shuffle-tree reduce over 16 kcc lanes; lane ends with b = kcc.
    const int b0 = lane & 1, b1 = (lane >> 1) & 1, b2 = (lane >> 2) & 1, b3 = (lane >> 3) & 1;
    float r1[8][2], r2[4][2], r3[2][2], z[2];
    #pragma unroll
    for (int i = 0; i < 8; ++i)
      #pragma unroll
      for (int g = 0; g < 2; ++g) {
        const float keep = b0 ? part[2*i+1][g] : part[2*i][g];
        const float send = b0 ? part[2*i][g]   : part[2*i+1][g];
        r1[i][g] = keep + __shfl_xor(send, 1, 64);
      }
    #pragma unroll
    for (int i = 0; i < 4; ++i)
      #pragma unroll
      for (int g = 0; g < 2; ++g) {
        const float keep = b1 ? r1[2*i+1][g] : r1[2*i][g];
        const float send = b1 ? r1[2*i][g]   : r1[2*i+1][g];
        r2[i][g] = keep + __shfl_xor(send, 2, 64);
      }
    #pragma unroll
    for (int i = 0; i < 2; ++i)
      #pragma unroll
      for (int g = 0; g < 2; ++g) {
        const float keep = b2 ? r2[2*i+1][g] : r2[2*i][g];
        const float send = b2 ? r2[2*i][g]   : r2[2*i+1][g];
        r3[i][g] = keep + __shfl_xor(send, 4, 64);
      }
    #pragma unroll
    for (int g = 0; g < 2; ++g) {
      const float keep = b3 ? r3[1][g] : r3[0][g];
      const float send = b3 ? r3[0][g] : r3[1][g];
      z[g] = keep + __shfl_xor(send, 8, 64);
    }
    z[0] += breg.x;
    z[1] += breg.y;

    // exchange with the partner thread holding the other gate pair (lane^16)
    const float o0 = __shfl_xor(z[0], 16, 64);
    const float o1 = __shfl_xor(z[1], 16, 64);
    const bool isif = (gp == 0);
    const float zi = isif ? z[0] : o0;
    const float zf = isif ? z[1] : o1;
    const float zg = isif ? o0 : z[0];
    const float zo = isif ? o1 : z[1];
    const float ig = 1.f/(1.f + expf(-zi));
    const float fg = 1.f/(1.f + expf(-zf));
    const float tg = tanhf(zg);
    const float og = 1.f/(1.f + expf(-zo));
    cst = fg*cst + ig*tg;                    // duplicated on partner, identical
    const float hval = og * tanhf(cst);

    // stage output tile in LDS, then coalesced 4-B agent stores
    if (isif) hst[kcc*9 + cl] = hval;
    __syncthreads();
    if (tid < 128) {
      const int b = tid >> 3, c = tid & 7;
      __hip_atomic_store(&hn[(size_t)(bq*16 + b)*HH + cg*8 + c], hst[b*9 + c],
                         __ATOMIC_RELAXED, __HIP_MEMORY_SCOPE_AGENT);
    }

    // drain stores, then publish readiness (single flag store, no RMW)
    asm volatile("s_waitcnt vmcnt(0)" ::: "memory");
    __syncthreads();
    if (tid == 0)
      __hip_atomic_store(&rdy[cg], (unsigned)(p+1), __ATOMIC_RELAXED, __HIP_MEMORY_SCOPE_AGENT);
  }
}

// ---------------------------------------------------------------------------
// K3: pots[b][t][tag] = [h_fw(t), h_bw(t)] @ wde^T + bde (+ boundaries)
// h layout: [d][phase][b][k]
// ---------------------------------------------------------------------------
__global__ __launch_bounds__(256) void k_dense(
    const float* __restrict__ h_all, const float* __restrict__ wde,
    const float* __restrict__ bde, const float* __restrict__ lb,
    const float* __restrict__ rb, float* __restrict__ pots)
{
  const int wv   = threadIdx.x >> 6;
  const int lane = threadIdx.x & 63;
  const int tok  = blockIdx.x*4 + wv;          // 0..32767
  const int b = tok >> 9, t = tok & 511;
  const float* hf = h_all + (size_t)(t+1)*HSTRIDE + (size_t)b*HH;
  const float* hb = h_all + DSTRIDE + (size_t)(SS-t)*HSTRIDE + (size_t)b*HH;
  float hr[16];
  *(float4*)&hr[0]  = *(const float4*)&hf[lane*8];
  *(float4*)&hr[4]  = *(const float4*)&hf[lane*8+4];
  *(float4*)&hr[8]  = *(const float4*)&hb[lane*8];
  *(float4*)&hr[12] = *(const float4*)&hb[lane*8+4];
  float s[9];
  #pragma unroll
  for (int tg = 0; tg < 9; ++tg) {
    const float* w0 = wde + tg*1024 + lane*8;
    const float* w1 = w0 + 512;
    const float4 a0 = *(const float4*)w0, a1 = *(const float4*)(w0+4);
    const float4 b0 = *(const float4*)w1, b1 = *(const float4*)(w1+4);
    s[tg] = hr[0]*a0.x + hr[1]*a0.y + hr[2]*a0.z + hr[3]*a0.w
          + hr[4]*a1.x + hr[5]*a1.y + hr[6]*a1.z + hr[7]*a1.w
          + hr[8]*b0.x + hr[9]*b0.y + hr[10]*b0.z + hr[11]*b0.w
          + hr[12]*b1.x + hr[13]*b1.y + hr[14]*b1.z + hr[15]*b1.w;
  }
  #pragma unroll
  for (int tg = 0; tg < 9; ++tg) {
    #pragma unroll
    for (int off = 32; off > 0; off >>= 1) s[tg] += __shfl_xor(s[tg], off, 64);
  }
  if (lane < 9) {
    float v = s[lane] + bde[lane];
    if (t == 0)   v += lb[lane];
    if (t == 511) v += rb[lane];
    pots[(size_t)tok*9 + lane] = v;
  }
}

// ---------------------------------------------------------------------------
// K4: Viterbi decode. One wave per batch row.
// ---------------------------------------------------------------------------
__global__ __launch_bounds__(64) void k_viterbi(
    const float* __restrict__ pots, const float* __restrict__ trans,
    float* __restrict__ dec)
{
  const int b = blockIdx.x;
  const int lane = threadIdx.x;
  __shared__ unsigned char bp[511*9];
  __shared__ unsigned char tl[512];
  __shared__ float af[9];
  const float* pb = pots + (size_t)b*512*9;
  float tr[9];
  #pragma unroll
  for (int i = 0; i < 9; ++i) tr[i] = (lane < 9) ? trans[i*9 + lane] : 0.f;
  float alpha = (lane < 9) ? pb[lane] : -3e38f;
  for (int t = 1; t < 512; ++t) {
    float best = -3e38f; int bi = 0;
    #pragma unroll
    for (int i = 0; i < 9; ++i) {
      const float sc = __shfl(alpha, i, 64) + tr[i];
      if (sc > best) { best = sc; bi = i; }     // strict > keeps first max (jnp.argmax)
    }
    if (lane < 9) {
      bp[(t-1)*9 + lane] = (unsigned char)bi;
      alpha = best + pb[(size_t)t*9 + lane];
    }
  }
  if (lane < 9) af[lane] = alpha;
  __syncthreads();
  if (lane == 0) {
    int tg = 0; float bv = af[0];
    #pragma unroll
    for (int i = 1; i < 9; ++i) if (af[i] > bv) { bv = af[i]; tg = i; }
    tl[511] = (unsigned char)tg;
    for (int t = 510; t >= 0; --t) { tg = bp[t*9 + tg]; tl[t] = (unsigned char)tg; }
  }
  __syncthreads();
  for (int t = lane; t < 512; t += 64) dec[(size_t)b*512 + t] = (float)tl[t];
}

// ---------------------------------------------------------------------------
extern "C" void kernel_launch(void* const* d_in, const int* in_sizes, int n_in,
                              void* d_out, int out_size, void* d_ws, size_t ws_size,
                              hipStream_t stream)
{
  const int*   inputs = (const int*)  d_in[0];
  const float* emb    = (const float*)d_in[1];
  const float* Wf     = (const float*)d_in[2];
  const float* Uf     = (const float*)d_in[3];
  const float* bf     = (const float*)d_in[4];
  const float* Wb     = (const float*)d_in[5];
  const float* Ub     = (const float*)d_in[6];
  const float* bb2    = (const float*)d_in[7];
  const float* Wd     = (const float*)d_in[8];
  const float* bd     = (const float*)d_in[9];
  const float* crfW   = (const float*)d_in[10];
  const float* crfb   = (const float*)d_in[11];
  const float* trans  = (const float*)d_in[12];
  const float* lb     = (const float*)d_in[13];
  const float* rb     = (const float*)d_in[14];

  float* ws   = (float*)d_ws;
  unsigned int* bars = (unsigned int*)d_ws;           // first 16 KB: ready flags
  float* hall = ws + 4096;                            // 2*513*32768 floats (~134.5 MB)
  float* wde  = hall + 2*DSTRIDE;                     // 9216 floats
  float* bde  = wde + 9216;                           // 16 floats

  float* dec  = (float*)d_out;                        // 32768 floats
  float* pots = dec + (size_t)BB*SS;                  // 294912 floats

  hipMemsetAsync(d_ws, 0, 16384, stream);

  k_wde<<<36, 256, 0, stream>>>(Wd, bd, crfW, crfb, wde, bde);

  {
    const int*   a0 = inputs; const float* a1 = emb;
    const float* a2 = Uf;  const float* a3 = Ub;
    const float* a4 = Wf;  const float* a5 = Wb;
    const float* a6 = bf;  const float* a7 = bb2;
    float* a8 = hall; unsigned int* a9 = bars;
    void* args[] = { &a0,&a1,&a2,&a3,&a4,&a5,&a6,&a7,&a8,&a9 };
    if (hipLaunchCooperativeKernel((void*)k_lstm, dim3(NWG), dim3(256),
                                   args, 0, stream) != hipSuccess) {
      k_lstm<<<NWG, 256, 0, stream>>>(inputs, emb, Uf, Ub, Wf, Wb, bf, bb2, hall, bars);
    }
  }

  k_dense<<<8192, 256, 0, stream>>>(hall, wde, bde, lb, rb, pots);
  k_viterbi<<<64, 64, 0, stream>>>(pots, trans, dec);
}

// Round 9
// 12094.701 us; speedup vs baseline: 1.5444x; 1.5444x over previous
//
#include <hip/hip_runtime.h>
#include <hip/hip_bf16.h>
#include <math.h>

#define BB 64
#define SS 512
#define EE 256
#define HH 512
#define GG 2048   // 4H
#define NWG 256
#define HSTRIDE 32768                       // floats per phase: 64 b * 512 k
#define DSTRIDE ((size_t)(SS+1)*HSTRIDE)    // floats per direction
#define SWZ(q) ((q) ^ (((q) >> 3) & 7))     // LDS quad swizzle

// ---------------------------------------------------------------------------
// K_pre: fold dense + CRF kernel:  wde[tag][k] = sum_m Wd[k][m]*crfW[m][tag]
// ---------------------------------------------------------------------------
__global__ void k_wde(const float* __restrict__ Wd, const float* __restrict__ bd,
                      const float* __restrict__ crfW, const float* __restrict__ crfb,
                      float* __restrict__ wde, float* __restrict__ bde)
{
  const int idx = blockIdx.x*256 + threadIdx.x;
  if (idx < 9*1024) {
    const int tag = idx >> 10, k = idx & 1023;
    float s = 0.f;
    #pragma unroll
    for (int m = 0; m < 9; ++m) s += Wd[k*9 + m] * crfW[m*9 + tag];
    wde[idx] = s;
  }
  if (idx < 9) {
    float s = crfb[idx];
    #pragma unroll
    for (int m = 0; m < 9; ++m) s += bd[m]*crfW[m*9 + idx];
    bde[idx] = s;
  }
}

// shuffle-tree reduce over the 16 kcc lanes; lane ends with b = kcc
__device__ __forceinline__ void tree16(const float (&part)[16][4], int lane, float (&z)[4])
{
  const int b0 = lane & 1, b1 = (lane >> 1) & 1, b2 = (lane >> 2) & 1, b3 = (lane >> 3) & 1;
  float r1[8][4], r2[4][4], r3[2][4];
  #pragma unroll
  for (int i = 0; i < 8; ++i)
    #pragma unroll
    for (int g = 0; g < 4; ++g) {
      const float keep = b0 ? part[2*i+1][g] : part[2*i][g];
      const float send = b0 ? part[2*i][g]   : part[2*i+1][g];
      r1[i][g] = keep + __shfl_xor(send, 1, 64);
    }
  #pragma unroll
  for (int i = 0; i < 4; ++i)
    #pragma unroll
    for (int g = 0; g < 4; ++g) {
      const float keep = b1 ? r1[2*i+1][g] : r1[2*i][g];
      const float send = b1 ? r1[2*i][g]   : r1[2*i+1][g];
      r2[i][g] = keep + __shfl_xor(send, 2, 64);
    }
  #pragma unroll
  for (int i = 0; i < 2; ++i)
    #pragma unroll
    for (int g = 0; g < 4; ++g) {
      const float keep = b2 ? r2[2*i+1][g] : r2[2*i][g];
      const float send = b2 ? r2[2*i][g]   : r2[2*i+1][g];
      r3[i][g] = keep + __shfl_xor(send, 4, 64);
    }
  #pragma unroll
  for (int g = 0; g < 4; ++g) {
    const float keep = b3 ? r3[1][g] : r3[0][g];
    const float send = b3 ? r3[0][g] : r3[1][g];
    z[g] = keep + __shfl_xor(send, 8, 64);
  }
}

// ---------------------------------------------------------------------------
// K2: persistent fused bidirectional LSTM (R7 topology, shadowed x-side).
// 256 WGs: wg -> group g = wg&7 (d = wg&1, bq = (wg>>1)&3), cg = wg>>3.
// WG tile = 16 b x 16 cols, 4 gates/thread, K split 16-way by kcc; U+W in
// VGPRs (resident — launch_bounds(256,1)). Critical path per step: poll ->
// h loads -> LDS park -> h@U -> tree -> gates -> scattered 4-B sc1 stores ->
// drain -> flag. x-side (tokens, emb staging, x@W partials, tree -> z_x)
// runs AFTER the flag store, in the next poll's shadow.
// h layout: h_all[d][phase 1..512][b][k]; phase-0 slot never read.
// ---------------------------------------------------------------------------
__global__ __launch_bounds__(256, 1) void k_lstm(
    const int* __restrict__ inputs, const float* __restrict__ emb,
    const float* __restrict__ Uf, const float* __restrict__ Ub,
    const float* __restrict__ Wf, const float* __restrict__ Wb,
    const float* __restrict__ bf, const float* __restrict__ bb2,
    float* __restrict__ h_all, unsigned int* __restrict__ bars)
{
  const int wg = blockIdx.x;
  const int d  = wg & 1;
  const int bq = (wg >> 1) & 3;
  const int cg = wg >> 3;                    // 0..31
  const float* __restrict__ U    = d ? Ub  : Uf;
  const float* __restrict__ W    = d ? Wb  : Wf;
  const float* __restrict__ bias = d ? bb2 : bf;
  float* __restrict__ h_d = h_all + (size_t)d * DSTRIDE;
  unsigned int* __restrict__ rdy = bars + (wg & 7)*64;   // 32 flags / group

  __shared__ float xs[4096];     // [16 b][256 k] quad-swizzled (16 KB)
  __shared__ float hs[8192];     // [16 b][512 k] quad-swizzled (32 KB)
  __shared__ int   tok_l[16];

  const int tid  = threadIdx.x;
  const int w    = tid >> 6;
  const int lane = tid & 63;
  const int kcc  = lane & 15;
  const int jj   = lane >> 4;
  const int col  = cg*16 + w*4 + jj;         // this thread's h-column

  // weights in registers: k-split 16-way by kcc
  float4 ureg[32];   // U[k = kcc*32+i][gates ifgo at col]
  #pragma unroll
  for (int i = 0; i < 32; ++i) {
    const float* ur = U + (size_t)(kcc*32 + i)*GG + col;
    ureg[i] = make_float4(ur[0], ur[512], ur[1024], ur[1536]);
  }
  float4 wreg[16];   // W[k = kcc*16+i][gates at col]
  #pragma unroll
  for (int i = 0; i < 16; ++i) {
    const float* wr = W + (size_t)(kcc*16 + i)*GG + col;
    wreg[i] = make_float4(wr[0], wr[512], wr[1024], wr[1536]);
  }
  const float4 breg = make_float4(bias[col], bias[512+col], bias[1024+col], bias[1536+col]);
  float cst = 0.f;                           // c-state for (b = bq*16+kcc, col)
  float zx[4];                               // x@W contribution for next step

  // shadow: stage tokens+x tile for time t, compute z_x (tree-reduced)
  auto shadow = [&](int t) {
    if (tid < 16) tok_l[tid] = inputs[(bq*16 + tid)*SS + t];
    __syncthreads();                         // tok ready
    #pragma unroll
    for (int r = 0; r < 4; ++r) {
      const int q = r*256 + tid, b = q >> 6, qx = q & 63;
      const float4 v = *(const float4*)&emb[(size_t)tok_l[b]*EE + qx*4];
      *(float4*)&xs[b*256 + SWZ(qx)*4] = v;
    }
    __syncthreads();                         // xs ready
    float px[16][4];
    #pragma unroll
    for (int b = 0; b < 16; ++b) { px[b][0]=0.f; px[b][1]=0.f; px[b][2]=0.f; px[b][3]=0.f; }
    #pragma unroll
    for (int b = 0; b < 16; ++b) {
      const float* xrow = &xs[b*256];
      #pragma unroll
      for (int i = 0; i < 4; ++i) {
        const int q = kcc*4 + i;
        const float4 hv = *(const float4*)&xrow[SWZ(q)*4];
        const float4 w0 = wreg[i*4+0], w1 = wreg[i*4+1], w2 = wreg[i*4+2], w3 = wreg[i*4+3];
        px[b][0] += hv.x*w0.x + hv.y*w1.x + hv.z*w2.x + hv.w*w3.x;
        px[b][1] += hv.x*w0.y + hv.y*w1.y + hv.z*w2.y + hv.w*w3.y;
        px[b][2] += hv.x*w0.z + hv.y*w1.z + hv.z*w2.z + hv.w*w3.z;
        px[b][3] += hv.x*w0.w + hv.y*w1.w + hv.z*w2.w + hv.w*w3.w;
      }
    }
    tree16(px, lane, zx);
  };

  // prologue: z_x for step 0
  shadow(d ? 511 : 0);

  #pragma unroll 1
  for (int p = 0; p < 512; ++p) {
    const float* __restrict__ hp = h_d + (size_t)p     * HSTRIDE;
    float* __restrict__ hn       = h_d + (size_t)(p+1) * HSTRIDE;

    // wave 0 polls this group's 32 producer flags (h(p) ready)
    if (p && w == 0) {
      for (;;) {
        unsigned int v = 0xFFFFFFFFu;
        if (lane < 32)
          v = __hip_atomic_load(&rdy[lane], __ATOMIC_RELAXED, __HIP_MEMORY_SCOPE_AGENT);
        if (__all((int)(v >= (unsigned)p))) break;
        __builtin_amdgcn_s_sleep(1);
      }
    }
    __syncthreads();                         // h(p) visible to all waves

    float zh[4] = {0.f, 0.f, 0.f, 0.f};
    if (p) {
      // h(p): coalesced plain loads -> LDS park (fine-grained vmcnt by compiler)
      float4 hld4[8];
      #pragma unroll
      for (int r = 0; r < 8; ++r) {
        const int q = r*256 + tid, b = q >> 7, qh = q & 127;
        hld4[r] = *(const float4*)&hp[(size_t)(bq*16 + b)*HH + qh*4];
      }
      #pragma unroll
      for (int r = 0; r < 8; ++r) {
        const int q = r*256 + tid, b = q >> 7, qh = q & 127;
        *(float4*)&hs[b*512 + SWZ(qh)*4] = hld4[r];
      }
      __syncthreads();                       // hs ready

      float part[16][4];
      #pragma unroll
      for (int b = 0; b < 16; ++b) { part[b][0]=0.f; part[b][1]=0.f; part[b][2]=0.f; part[b][3]=0.f; }
      #pragma unroll
      for (int b = 0; b < 16; ++b) {
        const float* hrow = &hs[b*512];
        #pragma unroll
        for (int i = 0; i < 8; ++i) {
          const int q = kcc*8 + i;
          const float4 hv = *(const float4*)&hrow[SWZ(q)*4];
          const float4 u0 = ureg[i*4+0], u1 = ureg[i*4+1], u2 = ureg[i*4+2], u3 = ureg[i*4+3];
          part[b][0] += hv.x*u0.x + hv.y*u1.x + hv.z*u2.x + hv.w*u3.x;
          part[b][1] += hv.x*u0.y + hv.y*u1.y + hv.z*u2.y + hv.w*u3.y;
          part[b][2] += hv.x*u0.z + hv.y*u1.z + hv.z*u2.z + hv.w*u3.z;
          part[b][3] += hv.x*u0.w + hv.y*u1.w + hv.z*u2.w + hv.w*u3.w;
        }
      }
      tree16(part, lane, zh);
    }

    // gates (Keras order i,f,g,o) for (b = bq*16+kcc, col)
    const float zi = zh[0] + zx[0] + breg.x;
    const float zf = zh[1] + zx[1] + breg.y;
    const float zg = zh[2] + zx[2] + breg.z;
    const float zo = zh[3] + zx[3] + breg.w;
    const float ig = 1.f/(1.f + expf(-zi));
    const float fg = 1.f/(1.f + expf(-zf));
    const float tg = tanhf(zg);
    const float og = 1.f/(1.f + expf(-zo));
    cst = fg*cst + ig*tg;
    const float hval = og * tanhf(cst);

    // direct 4-B write-through store (R5-proven, no amplification)
    __hip_atomic_store(&hn[(size_t)(bq*16 + kcc)*HH + col], hval,
                       __ATOMIC_RELAXED, __HIP_MEMORY_SCOPE_AGENT);

    // drain stores, then publish readiness (single flag store, no RMW)
    asm volatile("s_waitcnt vmcnt(0)" ::: "memory");
    __syncthreads();
    if (tid == 0)
      __hip_atomic_store(&rdy[cg], (unsigned)(p+1), __ATOMIC_RELAXED, __HIP_MEMORY_SCOPE_AGENT);

    // shadow: prepare z_x for step p+1 while peers converge
    int tn = d ? (510 - p) : (p + 1);
    tn = tn < 0 ? 0 : (tn > 511 ? 511 : tn);
    shadow(tn);
  }
}

// ---------------------------------------------------------------------------
// K3: pots[b][t][tag] = [h_fw(t), h_bw(t)] @ wde^T + bde (+ boundaries)
// h layout: [d][phase][b][k]
// ---------------------------------------------------------------------------
__global__ __launch_bounds__(256) void k_dense(
    const float* __restrict__ h_all, const float* __restrict__ wde,
    const float* __restrict__ bde, const float* __restrict__ lb,
    const float* __restrict__ rb, float* __restrict__ pots)
{
  const int wv   = threadIdx.x >> 6;
  const int lane = threadIdx.x & 63;
  const int tok  = blockIdx.x*4 + wv;          // 0..32767
  const int b = tok >> 9, t = tok & 511;
  const float* hf = h_all + (size_t)(t+1)*HSTRIDE + (size_t)b*HH;
  const float* hb = h_all + DSTRIDE + (size_t)(SS-t)*HSTRIDE + (size_t)b*HH;
  float hr[16];
  *(float4*)&hr[0]  = *(const float4*)&hf[lane*8];
  *(float4*)&hr[4]  = *(const float4*)&hf[lane*8+4];
  *(float4*)&hr[8]  = *(const float4*)&hb[lane*8];
  *(float4*)&hr[12] = *(const float4*)&hb[lane*8+4];
  float s[9];
  #pragma unroll
  for (int tg = 0; tg < 9; ++tg) {
    const float* w0 = wde + tg*1024 + lane*8;
    const float* w1 = w0 + 512;
    const float4 a0 = *(const float4*)w0, a1 = *(const float4*)(w0+4);
    const float4 b0 = *(const float4*)w1, b1 = *(const float4*)(w1+4);
    s[tg] = hr[0]*a0.x + hr[1]*a0.y + hr[2]*a0.z + hr[3]*a0.w
          + hr[4]*a1.x + hr[5]*a1.y + hr[6]*a1.z + hr[7]*a1.w
          + hr[8]*b0.x + hr[9]*b0.y + hr[10]*b0.z + hr[11]*b0.w
          + hr[12]*b1.x + hr[13]*b1.y + hr[14]*b1.z + hr[15]*b1.w;
  }
  #pragma unroll
  for (int tg = 0; tg < 9; ++tg) {
    #pragma unroll
    for (int off = 32; off > 0; off >>= 1) s[tg] += __shfl_xor(s[tg], off, 64);
  }
  if (lane < 9) {
    float v = s[lane] + bde[lane];
    if (t == 0)   v += lb[lane];
    if (t == 511) v += rb[lane];
    pots[(size_t)tok*9 + lane] = v;
  }
}

// ---------------------------------------------------------------------------
// K4: Viterbi decode. One wave per batch row.
// ---------------------------------------------------------------------------
__global__ __launch_bounds__(64) void k_viterbi(
    const float* __restrict__ pots, const float* __restrict__ trans,
    float* __restrict__ dec)
{
  const int b = blockIdx.x;
  const int lane = threadIdx.x;
  __shared__ unsigned char bp[511*9];
  __shared__ unsigned char tl[512];
  __shared__ float af[9];
  const float* pb = pots + (size_t)b*512*9;
  float tr[9];
  #pragma unroll
  for (int i = 0; i < 9; ++i) tr[i] = (lane < 9) ? trans[i*9 + lane] : 0.f;
  float alpha = (lane < 9) ? pb[lane] : -3e38f;
  for (int t = 1; t < 512; ++t) {
    float best = -3e38f; int bi = 0;
    #pragma unroll
    for (int i = 0; i < 9; ++i) {
      const float sc = __shfl(alpha, i, 64) + tr[i];
      if (sc > best) { best = sc; bi = i; }     // strict > keeps first max (jnp.argmax)
    }
    if (lane < 9) {
      bp[(t-1)*9 + lane] = (unsigned char)bi;
      alpha = best + pb[(size_t)t*9 + lane];
    }
  }
  if (lane < 9) af[lane] = alpha;
  __syncthreads();
  if (lane == 0) {
    int tg = 0; float bv = af[0];
    #pragma unroll
    for (int i = 1; i < 9; ++i) if (af[i] > bv) { bv = af[i]; tg = i; }
    tl[511] = (unsigned char)tg;
    for (int t = 510; t >= 0; --t) { tg = bp[t*9 + tg]; tl[t] = (unsigned char)tg; }
  }
  __syncthreads();
  for (int t = lane; t < 512; t += 64) dec[(size_t)b*512 + t] = (float)tl[t];
}

// ---------------------------------------------------------------------------
extern "C" void kernel_launch(void* const* d_in, const int* in_sizes, int n_in,
                              void* d_out, int out_size, void* d_ws, size_t ws_size,
                              hipStream_t stream)
{
  const int*   inputs = (const int*)  d_in[0];
  const float* emb    = (const float*)d_in[1];
  const float* Wf     = (const float*)d_in[2];
  const float* Uf     = (const float*)d_in[3];
  const float* bf     = (const float*)d_in[4];
  const float* Wb     = (const float*)d_in[5];
  const float* Ub     = (const float*)d_in[6];
  const float* bb2    = (const float*)d_in[7];
  const float* Wd     = (const float*)d_in[8];
  const float* bd     = (const float*)d_in[9];
  const float* crfW   = (const float*)d_in[10];
  const float* crfb   = (const float*)d_in[11];
  const float* trans  = (const float*)d_in[12];
  const float* lb     = (const float*)d_in[13];
  const float* rb     = (const float*)d_in[14];

  float* ws   = (float*)d_ws;
  unsigned int* bars = (unsigned int*)d_ws;           // first 16 KB: ready flags
  float* hall = ws + 4096;                            // 2*513*32768 floats (~134.5 MB)
  float* wde  = hall + 2*DSTRIDE;                     // 9216 floats
  float* bde  = wde + 9216;                           // 16 floats

  float* dec  = (float*)d_out;                        // 32768 floats
  float* pots = dec + (size_t)BB*SS;                  // 294912 floats

  hipMemsetAsync(d_ws, 0, 16384, stream);

  k_wde<<<36, 256, 0, stream>>>(Wd, bd, crfW, crfb, wde, bde);

  {
    const int*   a0 = inputs; const float* a1 = emb;
    const float* a2 = Uf;  const float* a3 = Ub;
    const float* a4 = Wf;  const float* a5 = Wb;
    const float* a6 = bf;  const float* a7 = bb2;
    float* a8 = hall; unsigned int* a9 = bars;
    void* args[] = { &a0,&a1,&a2,&a3,&a4,&a5,&a6,&a7,&a8,&a9 };
    if (hipLaunchCooperativeKernel((void*)k_lstm, dim3(NWG), dim3(256),
                                   args, 0, stream) != hipSuccess) {
      k_lstm<<<NWG, 256, 0, stream>>>(inputs, emb, Uf, Ub, Wf, Wb, bf, bb2, hall, bars);
    }
  }

  k_dense<<<8192, 256, 0, stream>>>(hall, wde, bde, lb, rb, pots);
  k_viterbi<<<64, 64, 0, stream>>>(pots, trans, dec);
}